// Round 11
// baseline (314.330 us; speedup 1.0000x reference)
//
#include <hip/hip_runtime.h>

typedef unsigned short u16;
typedef unsigned int u32;
typedef _Float16 half8 __attribute__((ext_vector_type(8)));
typedef __fp16 fp16x2 __attribute__((ext_vector_type(2)));
typedef float f32x16 __attribute__((ext_vector_type(16)));

union HU { uint4 u; half8 h; };
union PK { fp16x2 h; u32 u; };

__device__ __forceinline__ u16 f2h(float f) {
  union { _Float16 h; u16 u; } c;
  c.h = (_Float16)f;
  return c.u;
}

// async global->LDS DMA, 16 B per lane (lds dest = wave-uniform base + lane*16)
typedef const __attribute__((address_space(1))) u32 gu32;
typedef __attribute__((address_space(3))) u32 lu32;
__device__ __forceinline__ void gload_lds16(const void* g, void* l) {
  __builtin_amdgcn_global_load_lds((gu32*)g, (lu32*)l, 16, 0, 0);
}

// prep_w: pack weights (O=64,I=64,3,3) fp32 -> fp16 in A-fragment order
//   wbuf[((t*2+mt)*64+lane)*8+j] = w[m][c][rs], t = rs*4 + Q.
// Blocks >= 144 additionally zero xp's halo (rows 0/129 fully; slots 0/129
// of data rows) — ~2 MB of zero-writes, so prep_x stays branch-free.
__global__ __launch_bounds__(256) void prep_w(const float* __restrict__ w,
                                              u16* __restrict__ wbuf,
                                              u16* __restrict__ xp) {
  int bid = blockIdx.x, tid = threadIdx.x;
  if (bid < 144) {
    int idx = bid * 256 + tid;  // 36864 total
    int j    = idx & 7;
    int lane = (idx >> 3) & 63;
    int mt   = (idx >> 9) & 1;
    int t    = idx >> 10;
    int m  = mt * 32 + (lane & 31);
    int k  = t * 16 + (lane >> 5) * 8 + j;
    int rs = k >> 6;
    int c  = k & 63;
    wbuf[idx] = f2h(w[(m * 64 + c) * 9 + rs]);
    return;
  }
  // halo zeroing: 516 blocks x 256 = 132,096 uint4 writes, exact.
  int i = (bid - 144) * 256 + tid;
  int nb = i / 4128;
  int r  = i - nb * 4128;
  uint4* xp4 = (uint4*)xp;
  const uint4 zz = make_uint4(0u, 0u, 0u, 0u);
  if (r < 2080) {                       // halo rows 0 and 129 (1040 uint4 each)
    int hr  = (r < 1040) ? 0 : 129;
    int off = (r < 1040) ? r : r - 1040;
    xp4[(size_t)(nb * 130 + hr) * 1040 + off] = zz;
  } else {                              // px-halo slots 0/129 of data rows 1..128
    int r2 = r - 2080;                  // 128 rows x 8 cblk x 2 sides
    int row = 1 + (r2 >> 4);
    int cblk = (r2 >> 1) & 7;
    int side = r2 & 1;
    xp4[(size_t)(nb * 130 + row) * 1040 + cblk * 130 + side * 129] = zz;
  }
}

// prep_x: fp32 NCHW -> fp16 padded B-fragment layout (data region only):
//   xp[(((nb*130 + h+1)*8 + cblk)*130 + 1+px)*8 + j] = fp16(x[nb][cblk*8+j][h][px])
// Block = 256 thr x 4 rows, fully unrolled so the compiler overlaps row r+1's
// loads with row r's cvt/stores. Reads: 8 coalesced 512 B channel segments
// per wave; writes: 64 B/thread contiguous.
__global__ __launch_bounds__(256) void prep_x(const float* __restrict__ x,
                                              u16* __restrict__ xp) {
  int bid = blockIdx.x;  // 1024 = nb*32 + rg
  int nb = bid >> 5, rg = bid & 31;
  int tid = threadIdx.x;
  int cblk = tid >> 5;          // 0..7
  int px4 = (tid & 31) * 4;     // 0..124
  uint4* xp4 = (uint4*)xp;
#pragma unroll
  for (int rr = 0; rr < 4; ++rr) {
    int h = rg * 4 + rr;        // 0..127
    const float* xb = x + (((size_t)(nb * 64 + cblk * 8) * 128 + h) * 128 + px4);
    float4 f[8];
#pragma unroll
    for (int j = 0; j < 8; ++j) f[j] = *(const float4*)(xb + (size_t)j * 16384);
    size_t ob = (size_t)(nb * 130 + h + 1) * 1040 + cblk * 130 + 1 + px4;
#pragma unroll
    for (int p = 0; p < 4; ++p) {
      PK q0, q1, q2, q3;
      q0.h = __builtin_amdgcn_cvt_pkrtz(((const float*)&f[0])[p], ((const float*)&f[1])[p]);
      q1.h = __builtin_amdgcn_cvt_pkrtz(((const float*)&f[2])[p], ((const float*)&f[3])[p]);
      q2.h = __builtin_amdgcn_cvt_pkrtz(((const float*)&f[4])[p], ((const float*)&f[5])[p]);
      q3.h = __builtin_amdgcn_cvt_pkrtz(((const float*)&f[6])[p], ((const float*)&f[7])[p]);
      xp4[ob + p] = make_uint4(q0.u, q1.u, q2.u, q3.u);
    }
  }
}

// Implicit-GEMM conv: M = O = 64, N = pixels, K = 576 in 4 quarters of 16 ch.
// v11: A-IN-REGISTERS, x-ONLY LDS.  v9 proved pure-DMA staging is the best
// conv (<=78 us); v10 proved B must stay LDS-staged. Remaining v9 costs:
// wlds dbuf (36.9 KB LDS) + 2.0 ds_reads per 4-MFMA ktile. Fix: A-fragments
// load global->regs from the permanently-L2-hot 74 KB wbuf, staggered:
//   issue A(r0),A(r1) -> row0 -> issue A(r2), dma_x(Q+1) -> row1 -> row2
// Issue order makes every A-wait a COUNTED vmcnt (6/22/16, never 0), so the
// x-DMA stays in flight under rows 1-2. kloop = {2 B ds_read + 4 MFMA}/ktile
// (0.5 reads/MFMA). LDS = x dbuf only: 2 x 12 slabs x 130 x 8 = 49,920 B.
// Block = 512 thr (8 waves = rw4 x np2), 4 output rows x 128 px x 64 o;
// wave computes 64o x 64px, acc[2][2] = 64 AGPRs. launch_bounds(512,2) =
// 256-reg budget: A-window (<=72 VGPR) + acc fits with slack -> no spill
// (the r1/r4/r8 failure mode). Grid 1024 = 2 exact waves of 512 blocks.
// Padded xp -> zero bounds logic anywhere; LDS halo slots zeroed once.
// All LDS ops lane-contiguous 16 B -> conflict-free.
// XCD swizzle: 1024 % 8 == 0; wg = (bid&7)*128 + bid>>3.
__global__ __launch_bounds__(512, 2) void conv_mfma(
    const u16* __restrict__ xp, const u16* __restrict__ wbuf,
    const float* __restrict__ bias, float* __restrict__ out) {
  __shared__ u16 xlds[2][12 * 130 * 8];  // 2 x 24,960 B

  int tid = threadIdx.x;
  int lane = tid & 63;
  int wave = tid >> 6;  // 0..7
  int bid = blockIdx.x;
  int wg = ((bid & 7) << 7) | (bid >> 3);  // bijective XCD-contiguous remap
  int nb = wg >> 5;        // batch [0,32)
  int hg = wg & 31;        // row-group [0,32)
  int h0 = hg * 4;

  int l31 = lane & 31;
  int half = lane >> 5;
  int rw = wave >> 1;   // output row within block (0..3)
  int np = wave & 1;    // ntile pair: pixels np*64 + {0,32} + l31

  // zero LDS halo slots (0 and 129) of all 12 slabs in both buffers, once.
  if (tid < 48) {
    int b = tid / 24, r = tid % 24, sl = r >> 1, e = r & 1;
    *(uint4*)&xlds[b][(sl * 130 + e * 129) * 8] = make_uint4(0u, 0u, 0u, 0u);
  }

  f32x16 acc[2][2] = {};  // [mt][ntile]

  // DMA x quarter Q (cblks 2Q,2Q+1; padded rows h0..h0+5) into xl.
  // 24 tasks = (row6, cblk2, 64px-half2), 3 per wave; 1 KB per instr.
  auto dma_x = [&](int Q, u16* xl) {
#pragma unroll
    for (int s = 0; s < 3; ++s) {
      int id = s * 8 + wave;     // 0..23
      int row = id >> 2;         // 0..5
      int cblk = (id >> 1) & 1;
      int h64 = id & 1;
      int hrow = h0 + row;       // padded row index, always in [0,129]
      const u16* src = xp + (((size_t)(nb * 130 + hrow) * 8 + Q * 2 + cblk) * 130 +
                             1 + h64 * 64 + lane) * 8;
      gload_lds16(src, &xl[((row * 2 + cblk) * 130 + 1 + h64 * 64) * 8]);
    }
  };

  // issue the 6 A-fragments (rs = r*3.. , mt 0/1) of quarter Q, row r.
  auto loadA = [&](HU a[6], int Q, int r) {
#pragma unroll
    for (int k = 0; k < 6; ++k) {  // k = rs_local*2 + mt
      int rs = r * 3 + (k >> 1), mt = k & 1;
      a[k].u = *(const uint4*)&wbuf[((rs * 8 + Q * 2 + mt) * 64 + lane) * 8];
    }
  };

  // one kernel-row: 3 ktiles, {2 B ds_read_b128 + 4 MFMA} each.
  auto rowcomp = [&](int r, HU a[6], const u16* xl) {
    int sb = ((rw + r) * 2 + half) * 130;
#pragma unroll
    for (int s = 0; s < 3; ++s) {
      int ps = np * 64 + l31 + s;  // halo slot of ntile 0; ntile 1 at +32
      HU b0, b1;
      b0.u = *(const uint4*)&xl[(sb + ps) * 8];
      b1.u = *(const uint4*)&xl[(sb + ps + 32) * 8];
      acc[0][0] = __builtin_amdgcn_mfma_f32_32x32x16_f16(a[s * 2 + 0].h, b0.h, acc[0][0], 0, 0, 0);
      acc[0][1] = __builtin_amdgcn_mfma_f32_32x32x16_f16(a[s * 2 + 0].h, b1.h, acc[0][1], 0, 0, 0);
      acc[1][0] = __builtin_amdgcn_mfma_f32_32x32x16_f16(a[s * 2 + 1].h, b0.h, acc[1][0], 0, 0, 0);
      acc[1][1] = __builtin_amdgcn_mfma_f32_32x32x16_f16(a[s * 2 + 1].h, b1.h, acc[1][1], 0, 0, 0);
    }
  };

  // ---- schedule ----
  dma_x(0, xlds[0]);
  __syncthreads();  // drains prologue DMA
#pragma unroll
  for (int Q = 0; Q < 4; ++Q) {
    const u16* xl = xlds[Q & 1];
    HU a0[6], a1[6], a2[6];
    loadA(a0, Q, 0);
    loadA(a1, Q, 1);
    rowcomp(0, a0, xl);              // waits vmcnt(6) — a1 stays in flight
    loadA(a2, Q, 2);
    if (Q < 3) dma_x(Q + 1, xlds[(Q + 1) & 1]);  // in flight under rows 1-2
    rowcomp(1, a1, xl);              // waits vmcnt(22)
    rowcomp(2, a2, xl);              // waits vmcnt(16) — DMA still in flight
    if (Q < 3) __syncthreads();      // DMA completed under rows 1-2
  }

  // ---- epilogue: C/D layout col = lane&31 (pixel), row = (reg&3)+8*(reg>>2)+4*half (o) ----
  int h = h0 + rw;
#pragma unroll
  for (int mt = 0; mt < 2; ++mt) {
#pragma unroll
    for (int i = 0; i < 2; ++i) {
      int p = np * 64 + i * 32 + l31;
      size_t ob = (size_t)nb * 64 * 16384 + (size_t)h * 128 + p;
#pragma unroll
      for (int reg = 0; reg < 16; ++reg) {
        int o = mt * 32 + (reg & 3) + 8 * (reg >> 2) + 4 * half;
        out[ob + (size_t)o * 16384] = acc[mt][i][reg] + bias[o];
      }
    }
  }
}

extern "C" void kernel_launch(void* const* d_in, const int* in_sizes, int n_in,
                              void* d_out, int out_size, void* d_ws, size_t ws_size,
                              hipStream_t stream) {
  const float* x = (const float*)d_in[0];
  const float* w = (const float*)d_in[1];
  const float* b = (const float*)d_in[2];
  float* out = (float*)d_out;
  // workspace: wbuf (73,728 B) at 0; padded xp (69.2 MB) at 128 KB offset.
  u16* wbuf = (u16*)d_ws;
  u16* xp = (u16*)((char*)d_ws + (128 << 10));

  prep_w<<<dim3(660), dim3(256), 0, stream>>>(w, wbuf, xp);
  prep_x<<<dim3(1024), dim3(256), 0, stream>>>(x, xp);
  conv_mfma<<<dim3(1024), dim3(512), 0, stream>>>(xp, wbuf, b, out);
}

// Round 12
// 269.332 us; speedup vs baseline: 1.1671x; 1.1671x over previous
//
#include <hip/hip_runtime.h>

typedef unsigned short u16;
typedef unsigned int u32;
typedef _Float16 half8 __attribute__((ext_vector_type(8)));
typedef __fp16 fp16x2 __attribute__((ext_vector_type(2)));
typedef float f32x16 __attribute__((ext_vector_type(16)));

union HU { uint4 u; half8 h; };
union PK { fp16x2 h; u32 u; };

__device__ __forceinline__ u16 f2h(float f) {
  union { _Float16 h; u16 u; } c;
  c.h = (_Float16)f;
  return c.u;
}

// async global->LDS DMA, 16 B per lane (lds dest = wave-uniform base + lane*16)
typedef const __attribute__((address_space(1))) u32 gu32;
typedef __attribute__((address_space(3))) u32 lu32;
__device__ __forceinline__ void gload_lds16(const void* g, void* l) {
  __builtin_amdgcn_global_load_lds((gu32*)g, (lu32*)l, 16, 0, 0);
}

// Pack weights (O=64, I=64, 3, 3) fp32 -> fp16 in exact A-fragment order:
// wbuf[((t*2 + mt)*64 + lane)*8 + j] = w[m][c][rs]
//   m = mt*32 + (lane&31), k = t*16 + (lane>>5)*8 + j, rs = k>>6, c = k&63
// K ordering: k = rs*64 + c (rs-major, c-minor); ktile t = rs*4 + Q (16-ch quarter).
__global__ void prep_w(const float* __restrict__ w, u16* __restrict__ wbuf) {
  int idx = blockIdx.x * 256 + threadIdx.x;  // 36864 total
  int j    = idx & 7;
  int lane = (idx >> 3) & 63;
  int mt   = (idx >> 9) & 1;
  int t    = idx >> 10;
  int m  = mt * 32 + (lane & 31);
  int k  = t * 16 + (lane >> 5) * 8 + j;
  int rs = k >> 6;
  int c  = k & 63;
  wbuf[idx] = f2h(w[(m * 64 + c) * 9 + rs]);
}

// Implicit-GEMM conv: M = O = 64, N = pixels, K = 576 in 4 quarters of 16 ch.
// v12: PRODUCER/CONSUMER WAVE SPECIALIZATION.
// Session evidence: single-kernel lockstep {stage -> barrier -> kloop} is
// pinned at 96-106 us across 4 schedules (r5-r8); r9's ablation proved the
// in-kernel staging machinery is the cost (conv <=78 us without it); but a
// separate prep_x pass costs more than it saves (r9-r11, kernels 126-156).
// Fix: keep staging in-kernel but move it OFF the critical path — 512 thr =
// 4 PRODUCER waves (stage x(Q+1): fp32 loads -> pkrtz -> ds_write; fire
// dma_w(Q+1)) + 4 CONSUMER waves (pure kloop on quarter Q). Staging latency
// runs concurrently with MFMA; the per-phase barrier drain is cheap
// (producer VMEM already consumed by cvt; dma_w had a full phase in flight).
// Consumer wave (cw = rw2 x np2): 64o x 64px, per ktile {2 A + 2 B
// ds_read_b128 -> 4 MFMA} = 1.0 reads/MFMA, acc[2][2] = 64 AGPRs.
// s_setprio(1) around the MFMA cluster: T5's prereq (role-diverse waves on
// the CU) is now satisfied — producers yield issue slots to MFMA waves.
// LDS: xlds dbuf 2 x 16,640 + wlds dbuf 2 x 18,432 = 70,144 B -> 2 blocks/CU
// (8 consumer + 8 producer waves per CU). launch_bounds(512,4) = 128-reg
// budget; consumer path ~104 (64 acc + frags + addr), producer ~50 -> no
// spill (WRITE_SIZE == 131 MB is the tell).
// Halo-padded pixel axis (slots 0/129 zeroed once per buffer) -> no bounds
// logic in kloop. All LDS ops lane-contiguous 16 B -> conflict-free.
// XCD swizzle: 2048 % 8 == 0; wg = (bid&7)*256 + bid>>3.
__global__ __launch_bounds__(512, 4) void conv_mfma(
    const float* __restrict__ x, const u16* __restrict__ wbuf,
    const float* __restrict__ bias, float* __restrict__ out) {
  __shared__ u16 xlds[2][8 * 130 * 8];   // 2 x 16,640 B
  __shared__ u16 wlds[2][18 * 512];      // 2 x 18,432 B

  int tid = threadIdx.x;
  int lane = tid & 63;
  int wave = tid >> 6;  // 0..7
  int bid = blockIdx.x;
  int wg = ((bid & 7) << 8) | (bid >> 3);  // bijective XCD-contiguous remap
  int nb = wg >> 6;        // batch [0,32)
  int hg = wg & 63;        // row-group [0,64)
  int h0 = hg * 2;

  const bool producer = (wave >= 4);
  int role = wave & 3;     // consumer id cw / producer id pid

  int l31 = lane & 31;
  int half = lane >> 5;
  int rw = role >> 1;      // consumer: output row within block (0..1)
  int np = role & 1;       // consumer: ntile pair, pixels np*64 + {0,32} + l31

  // zero halo slots (0 and 129) of all 8 slabs in BOTH x buffers, once.
  if (tid < 32) {
    int b = tid >> 4, sl = (tid >> 1) & 7, e = tid & 1;
    *(uint4*)&xlds[b][(sl * 130 + e * 129) * 8] = make_uint4(0u, 0u, 0u, 0u);
  }

  f32x16 acc[2][2] = {};  // [mt][ntile] — consumers only

  // PRODUCER: stage x channels Q*16..+15, rows h0-1..h0+2 -> xl (fp32->fp16).
  // 16 tasks = (row4, cblk2, whalf2); 4 per producer wave.
  auto stage_x = [&](int Q, u16* xl) {
#pragma unroll
    for (int s4 = 0; s4 < 4; ++s4) {
      int id = s4 * 4 + role;     // 0..15
      int row = id >> 2;          // 0..3
      int cblk = (id >> 1) & 1;
      int wh = id & 1;
      int hin = h0 - 1 + row;
      int c0 = Q * 16 + cblk * 8;
      const float* base = x + (((size_t)(nb * 64 + c0) * 128 + hin) * 128);
      int wp = wh * 64 + lane;
      uint4 v = make_uint4(0u, 0u, 0u, 0u);
      if (hin >= 0 && hin < 128) {
        float f[8];
#pragma unroll
        for (int j = 0; j < 8; ++j) f[j] = base[(size_t)j * 16384 + wp];
        PK p0, p1, p2, p3;
        p0.h = __builtin_amdgcn_cvt_pkrtz(f[0], f[1]);
        p1.h = __builtin_amdgcn_cvt_pkrtz(f[2], f[3]);
        p2.h = __builtin_amdgcn_cvt_pkrtz(f[4], f[5]);
        p3.h = __builtin_amdgcn_cvt_pkrtz(f[6], f[7]);
        v = make_uint4(p0.u, p1.u, p2.u, p3.u);
      }
      *(uint4*)&xl[((row * 2 + cblk) * 130 + 1 + wp) * 8] = v;
    }
  };

  // PRODUCER: DMA quarter Q's 18 A-fragments (rs9 x mt2, 1 KB each) into wl.
  auto dma_w = [&](int Q, u16* wl) {
#pragma unroll
    for (int s5 = 0; s5 < 5; ++s5) {
      int f = s5 * 4 + role;  // 0..19, valid < 18
      if (f < 18) {
        int gf = (f >> 1) * 8 + Q * 2 + (f & 1);  // wbuf frag (rs*4+Q)*2+mt
        gload_lds16(&wbuf[gf * 512 + lane * 8], &wl[f * 512]);
      }
    }
  };

  // CONSUMER: 9 ktiles, per ktile {2 A + 2 B ds_read, 4 MFMA}.
  auto kloop = [&](const u16* xl, const u16* wl) {
    __builtin_amdgcn_s_setprio(1);
#pragma unroll
    for (int r = 0; r < 3; ++r) {
      int row = rw + r;                 // staged row index 0..3
      int sb = (row * 2 + half) * 130;  // lane-half picks the cblk
#pragma unroll
      for (int s = 0; s < 3; ++s) {
        int rs = r * 3 + s;
        int ps = np * 64 + l31 + s;  // halo slot of ntile 0; ntile 1 at +32
        HU a0, a1, b0, b1;
        a0.u = *(const uint4*)&wl[(rs * 2 + 0) * 512 + lane * 8];
        a1.u = *(const uint4*)&wl[(rs * 2 + 1) * 512 + lane * 8];
        b0.u = *(const uint4*)&xl[(sb + ps) * 8];
        b1.u = *(const uint4*)&xl[(sb + ps + 32) * 8];
        acc[0][0] = __builtin_amdgcn_mfma_f32_32x32x16_f16(a0.h, b0.h, acc[0][0], 0, 0, 0);
        acc[0][1] = __builtin_amdgcn_mfma_f32_32x32x16_f16(a0.h, b1.h, acc[0][1], 0, 0, 0);
        acc[1][0] = __builtin_amdgcn_mfma_f32_32x32x16_f16(a1.h, b0.h, acc[1][0], 0, 0, 0);
        acc[1][1] = __builtin_amdgcn_mfma_f32_32x32x16_f16(a1.h, b1.h, acc[1][1], 0, 0, 0);
      }
    }
    __builtin_amdgcn_s_setprio(0);
  };

  // ---- schedule: producers always one quarter ahead of consumers ----
  if (producer) {
    dma_w(0, wlds[0]);
    stage_x(0, xlds[0]);
  }
  __syncthreads();  // x(0) + w(0) ready

#pragma unroll
  for (int Q = 0; Q < 4; ++Q) {
    if (producer) {
      if (Q < 3) {
        dma_w(Q + 1, wlds[(Q + 1) & 1]);   // fire-and-forget, drains at barrier
        stage_x(Q + 1, xlds[(Q + 1) & 1]); // overlaps consumers' kloop(Q)
      }
    } else {
      kloop(xlds[Q & 1], wlds[Q & 1]);
    }
    if (Q < 3) __syncthreads();  // phase Q+1 buffers ready; Q buffers free
  }

  if (producer) return;

  // ---- epilogue (consumers): C/D col = lane&31 (pixel),
  //      row = (reg&3)+8*(reg>>2)+4*half (o) ----
  int h = h0 + rw;
#pragma unroll
  for (int mt = 0; mt < 2; ++mt) {
#pragma unroll
    for (int i = 0; i < 2; ++i) {
      int p = np * 64 + i * 32 + l31;
      size_t ob = (size_t)nb * 64 * 16384 + (size_t)h * 128 + p;
#pragma unroll
      for (int reg = 0; reg < 16; ++reg) {
        int o = mt * 32 + (reg & 3) + 8 * (reg >> 2) + 4 * half;
        out[ob + (size_t)o * 16384] = acc[mt][i][reg] + bias[o];
      }
    }
  }
}

extern "C" void kernel_launch(void* const* d_in, const int* in_sizes, int n_in,
                              void* d_out, int out_size, void* d_ws, size_t ws_size,
                              hipStream_t stream) {
  const float* x = (const float*)d_in[0];
  const float* w = (const float*)d_in[1];
  const float* b = (const float*)d_in[2];
  float* out = (float*)d_out;
  u16* wbuf = (u16*)d_ws;  // 36864 fp16 = 73728 B of scratch

  prep_w<<<dim3(144), dim3(256), 0, stream>>>(w, wbuf);
  conv_mfma<<<dim3(2048), dim3(512), 0, stream>>>(x, wbuf, b, out);
}

// Round 13
// 263.721 us; speedup vs baseline: 1.1919x; 1.0213x over previous
//
#include <hip/hip_runtime.h>

typedef unsigned short u16;
typedef unsigned int u32;
typedef _Float16 half8 __attribute__((ext_vector_type(8)));
typedef __fp16 fp16x2 __attribute__((ext_vector_type(2)));
typedef float f32x16 __attribute__((ext_vector_type(16)));

union HU { uint4 u; half8 h; };
union PK { fp16x2 h; u32 u; };

__device__ __forceinline__ u16 f2h(float f) {
  union { _Float16 h; u16 u; } c;
  c.h = (_Float16)f;
  return c.u;
}

// async global->LDS DMA, 16 B per lane (lds dest = wave-uniform base + lane*16;
// global source address is per-lane)
typedef const __attribute__((address_space(1))) u32 gu32;
typedef __attribute__((address_space(3))) u32 lu32;
__device__ __forceinline__ void gload_lds16(const void* g, void* l) {
  __builtin_amdgcn_global_load_lds((gu32*)g, (lu32*)l, 16, 0, 0);
}

// Pack weights (O=64, I=64, 3, 3) fp32 -> fp16 in exact A-fragment order:
// wbuf[((t*2 + mt)*64 + lane)*8 + j] = w[m][c][rs]
//   m = mt*32 + (lane&31), k = t*16 + (lane>>5)*8 + j, rs = k>>6, c = k&63
// K ordering: k = rs*64 + c (rs-major, c-minor); ktile t = rs*4 + Q (16-ch quarter).
__global__ void prep_w(const float* __restrict__ w, u16* __restrict__ wbuf) {
  int idx = blockIdx.x * 256 + threadIdx.x;  // 36864 total
  int j    = idx & 7;
  int lane = (idx >> 3) & 63;
  int mt   = (idx >> 9) & 1;
  int t    = idx >> 10;
  int m  = mt * 32 + (lane & 31);
  int k  = t * 16 + (lane >> 5) * 8 + j;
  int rs = k >> 6;
  int c  = k & 63;
  wbuf[idx] = f2h(w[(m * 64 + c) * 9 + rs]);
}

// Implicit-GEMM conv: M = O = 64, N = pixels, K = 576 in 4 quarters of 16 ch.
// v13: DMA-fp32 + IN-LDS CONVERT.
// Session evidence: every schedule staging x through VGPRs (fp32 load ->
// pkrtz -> ds_write) lands at 96-109 us (v5-v8, v12) — the exposed
// global->VGPR latency inside each phase is the invariant cost. v9 (pure
// global_load_lds DMA) broke to <=78 us but paid a 46 us prep kernel.
// This round gets DMA staging without the prep pass: DMA the RAW FP32 x
// into an LDS slab (fire-and-forget, lands under the previous kloop), then
// a short wave-parallel in-LDS transpose+convert (ds_read_b128 fp32 ->
// pkrtz -> ds_write_b128 fp16 into the halo-padded B-tile). Per-phase
// critical path = convert (~500 cyc LDS/VALU throughput work) + kloop;
// no global latency on it anywhere.
// Block = 1 output row x 128 px x 64 o; 256 thr = 4 waves = (mt2, np2);
// wave = one mtile x two 32-px ntiles, acc[2] = 32 AGPRs, per ktile
// {1 A + 2 B ds_read_b128 -> 2 MFMA}. Grid 4096 (32 nb x 128 h).
// LDS: xf32 [row3][cpair8][c2][px128] fp32 = 24,576 B (DMA dest, linear)
//    + x16  [row3][cblk2][slot130][ch8] fp16 = 12,480 B (halo-padded B-tile)
//    + wlds dbuf 2 x 18,432 B = 73,920 B total -> 2 blocks/CU (8 waves/CU).
// Schedule per quarter: convert(Q) -> barrier -> issue DMA(Q+1) (x fp32 + w)
// -> kloop(Q) -> barrier (drains DMA under kloop's shadow). 2 barriers/phase.
// OOB input rows: their xf32 slab is pre-zeroed once and never DMA'd (the
// skip is task-uniform), so converts yield fp16 zeros — no bounds logic.
// launch_bounds(256,2): 256-reg budget, nothing held across kloop -> no
// spill (WRITE_SIZE == 131 MB is the tell).
// XCD swizzle: 4096 % 8 == 0; wg = (bid&7)*512 + bid>>3.
__global__ __launch_bounds__(256, 2) void conv_mfma(
    const float* __restrict__ x, const u16* __restrict__ wbuf,
    const float* __restrict__ bias, float* __restrict__ out) {
  __shared__ float xf32[3 * 8 * 2 * 128];  // 24,576 B raw fp32 staging
  __shared__ u16 x16[3 * 2 * 130 * 8];     // 12,480 B fp16 B-tile
  __shared__ u16 wlds[2][18 * 512];        // 2 x 18,432 B

  int tid = threadIdx.x;
  int lane = tid & 63;
  int wave = tid >> 6;  // 0..3
  int bid = blockIdx.x;
  int wg = ((bid & 7) << 9) | (bid >> 3);  // bijective XCD-contiguous remap
  int nb = wg >> 7;    // batch [0,32)
  int h  = wg & 127;   // output row [0,128)

  int l31 = lane & 31;
  int half = lane >> 5;
  int mt = wave >> 1;  // this wave's mtile
  int np = wave & 1;   // ntile pair: pixels np*64 + {0,32} + l31

  const uint4 zz = make_uint4(0u, 0u, 0u, 0u);
  // zero fp16 halo slots (0 and 129) of all 6 slabs, once (convert only
  // writes slots 1..128).
  if (tid < 12) {
    int sl = tid >> 1, e = tid & 1;
    *(uint4*)&x16[(sl * 130 + e * 129) * 8] = zz;
  }
  // zero the OOB fp32 row slab once; it is never DMA'd (task-uniform skip),
  // so it stays zero across all 4 quarters -> converts to fp16 zeros.
  if (h == 0) {
#pragma unroll
    for (int i = 0; i < 2; ++i) ((uint4*)xf32)[i * 256 + tid] = zz;        // row 0
  } else if (h == 127) {
#pragma unroll
    for (int i = 0; i < 2; ++i) ((uint4*)xf32)[1024 + i * 256 + tid] = zz;  // row 2
  }

  f32x16 acc[2] = {};  // [ntile]

  // DMA quarter Q's raw fp32 x (rows h-1..h+1, 16 ch) into xf32.
  // 24 tasks = (row3, cpair8); lane -> c = cpair*2 + (lane>>5),
  // px = (lane&31)*4 (16 B). Dest: task base + lane*16 (HW).
  auto dma_x = [&](int Q) {
#pragma unroll
    for (int s = 0; s < 6; ++s) {
      int id = s * 4 + wave;  // 0..23
      int row = id >> 3;      // 0..2
      int cpair = id & 7;
      int hin = h - 1 + row;
      if (hin >= 0 && hin < 128) {  // task-uniform branch
        int c = Q * 16 + cpair * 2 + (lane >> 5);
        const float* src =
            x + (((size_t)(nb * 64 + c) * 128 + hin) * 128 + (lane & 31) * 4);
        gload_lds16(src, (char*)xf32 + (row * 8 + cpair) * 1024);
      }
    }
  };

  // DMA quarter Q's 18 A-fragments (rs9 x mt2, 1 KB each) into wl.
  auto dma_w = [&](int Q, u16* wl) {
#pragma unroll
    for (int s5 = 0; s5 < 5; ++s5) {
      int f = s5 * 4 + wave;  // 0..19, valid < 18
      if (f < 18) {
        int gf = (f >> 1) * 8 + Q * 2 + (f & 1);  // wbuf frag (rs*4+Q)*2+mt
        gload_lds16(&wbuf[gf * 512 + lane * 8], &wl[f * 512]);
      }
    }
  };

  // in-LDS transpose+convert: xf32 -> x16. 192 chunks = (row3, cblk2,
  // pxchunk32); chunk = 4 px x 8 ch: 8 ds_read_b128 + 16 pkrtz +
  // 4 ds_write_b128. Channel reconstruction: ch j of cblk lives at
  // cpair = cblk*4 + (j>>1), c2 = j&1  ->  c = cblk*8 + j  (exact).
  auto convert = [&]() {
    if (tid < 192) {
      int px4c = tid & 31;
      int cblk = (tid >> 5) & 1;
      int row = tid >> 6;  // 0..2
      float4 fj[8];
#pragma unroll
      for (int j = 0; j < 8; ++j) {
        int off = ((row * 8 + cblk * 4 + (j >> 1)) * 2 + (j & 1)) * 128 + px4c * 4;
        fj[j] = *(const float4*)&xf32[off];
      }
#pragma unroll
      for (int p = 0; p < 4; ++p) {
        PK q0, q1, q2, q3;
        q0.h = __builtin_amdgcn_cvt_pkrtz(((const float*)&fj[0])[p], ((const float*)&fj[1])[p]);
        q1.h = __builtin_amdgcn_cvt_pkrtz(((const float*)&fj[2])[p], ((const float*)&fj[3])[p]);
        q2.h = __builtin_amdgcn_cvt_pkrtz(((const float*)&fj[4])[p], ((const float*)&fj[5])[p]);
        q3.h = __builtin_amdgcn_cvt_pkrtz(((const float*)&fj[6])[p], ((const float*)&fj[7])[p]);
        *(uint4*)&x16[((row * 2 + cblk) * 130 + px4c * 4 + p + 1) * 8] =
            make_uint4(q0.u, q1.u, q2.u, q3.u);
      }
    }
  };

  // 9 ktiles: per ktile {1 A + 2 B ds_read_b128, 2 MFMA}.
  auto kloop = [&](const u16* wl) {
#pragma unroll
    for (int r = 0; r < 3; ++r) {
      int sb = (r * 2 + half) * 130;  // lane-half picks the cblk
#pragma unroll
      for (int s = 0; s < 3; ++s) {
        int rs = r * 3 + s;
        int ps = np * 64 + l31 + s;  // halo slot of ntile 0; ntile 1 at +32
        HU a, b0, b1;
        a.u  = *(const uint4*)&wl[(rs * 2 + mt) * 512 + lane * 8];
        b0.u = *(const uint4*)&x16[(sb + ps) * 8];
        b1.u = *(const uint4*)&x16[(sb + ps + 32) * 8];
        acc[0] = __builtin_amdgcn_mfma_f32_32x32x16_f16(a.h, b0.h, acc[0], 0, 0, 0);
        acc[1] = __builtin_amdgcn_mfma_f32_32x32x16_f16(a.h, b1.h, acc[1], 0, 0, 0);
      }
    }
  };

  // ---- schedule ----
  dma_x(0);
  dma_w(0, wlds[0]);
  __syncthreads();  // drains prologue DMA (+ zero-inits visible)
#pragma unroll
  for (int Q = 0; Q < 4; ++Q) {
    convert();        // xf32 -> x16 (pure LDS + VALU)
    __syncthreads();  // x16 ready for all waves; xf32 free for next DMA
    if (Q < 3) {
      dma_x(Q + 1);                      // fire-and-forget into xf32
      dma_w(Q + 1, wlds[(Q + 1) & 1]);   // fire-and-forget into other wl
    }
    kloop(wlds[Q & 1]);
    if (Q < 3) __syncthreads();  // drains DMA (landed under kloop); x16 free
  }

  // ---- epilogue: C/D layout col = lane&31 (pixel), row = (reg&3)+8*(reg>>2)+4*half (o) ----
#pragma unroll
  for (int i = 0; i < 2; ++i) {
    int p = np * 64 + i * 32 + l31;
    size_t ob = (size_t)nb * 64 * 16384 + (size_t)h * 128 + p;
#pragma unroll
    for (int reg = 0; reg < 16; ++reg) {
      int o = mt * 32 + (reg & 3) + 8 * (reg >> 2) + 4 * half;
      out[ob + (size_t)o * 16384] = acc[i][reg] + bias[o];
    }
  }
}

extern "C" void kernel_launch(void* const* d_in, const int* in_sizes, int n_in,
                              void* d_out, int out_size, void* d_ws, size_t ws_size,
                              hipStream_t stream) {
  const float* x = (const float*)d_in[0];
  const float* w = (const float*)d_in[1];
  const float* b = (const float*)d_in[2];
  float* out = (float*)d_out;
  u16* wbuf = (u16*)d_ws;  // 36864 fp16 = 73728 B of scratch

  prep_w<<<dim3(144), dim3(256), 0, stream>>>(w, wbuf);
  conv_mfma<<<dim3(4096), dim3(256), 0, stream>>>(x, wbuf, b, out);
}

// Round 14
// 255.422 us; speedup vs baseline: 1.2306x; 1.0325x over previous
//
#include <hip/hip_runtime.h>

typedef unsigned short u16;
typedef unsigned int u32;
typedef _Float16 half8 __attribute__((ext_vector_type(8)));
typedef __fp16 fp16x2 __attribute__((ext_vector_type(2)));
typedef float f32x16 __attribute__((ext_vector_type(16)));

union HU { uint4 u; half8 h; };
union PK { fp16x2 h; u32 u; };

__device__ __forceinline__ u16 f2h(float f) {
  union { _Float16 h; u16 u; } c;
  c.h = (_Float16)f;
  return c.u;
}

// async global->LDS DMA, 16 B per lane (lds dest = wave-uniform base + lane*16)
typedef const __attribute__((address_space(1))) u32 gu32;
typedef __attribute__((address_space(3))) u32 lu32;
__device__ __forceinline__ void gload_lds16(const void* g, void* l) {
  __builtin_amdgcn_global_load_lds((gu32*)g, (lu32*)l, 16, 0, 0);
}

// Pack weights (O=64, I=64, 3, 3) fp32 -> fp16 in exact A-fragment order:
// wbuf[((t*2 + mt)*64 + lane)*8 + j] = w[m][c][rs]
//   m = mt*32 + (lane&31), k = t*16 + (lane>>5)*8 + j, rs = k>>6, c = k&63
// K ordering: k = rs*64 + c (rs-major, c-minor); ktile t = rs*4 + Q (16-ch quarter).
__global__ void prep_w(const float* __restrict__ w, u16* __restrict__ wbuf) {
  int idx = blockIdx.x * 256 + threadIdx.x;  // 36864 total
  int j    = idx & 7;
  int lane = (idx >> 3) & 63;
  int mt   = (idx >> 9) & 1;
  int t    = idx >> 10;
  int m  = mt * 32 + (lane & 31);
  int k  = t * 16 + (lane >> 5) * 8 + j;
  int rs = k >> 6;
  int c  = k & 63;
  wbuf[idx] = f2h(w[(m * 64 + c) * 9 + rs]);
}

// Implicit-GEMM conv: M = O = 64, N = pixels, K = 576.
// FINAL (v6, session-best: conv 96.5 us, bench 256.0, 0 conflicts, no spill).
// Session evidence for this choice:
//  * A-fragments MUST be LDS-staged (global A = L2-latency wall: r0/r2/r10/r11).
//  * x staged through VGPRs (load->pkrtz->ds_write) per 16-ch quarter; every
//    alternative (reg-pipeline v8, producer/consumer v12, DMA+in-LDS-convert
//    v13, two-kernel pre-transpose v9-v11) measured equal or worse.
//  * Wave shape (rw, np) computes BOTH mtiles x 2 ntiles (64o x 64px):
//    per ktile {2 A + 2 B ds_reads -> 4 MFMAs} = 1.0 reads/MFMA.
//    acc = 4 x f32x16 = 64 AGPRs; launch_bounds(512,4) = 128-reg budget;
//    NOTHING held in regs across a K-loop (r1/r4/r8 spill lesson).
//  * Residual ~96 us is phase-serialization (vmcnt(0) drain before each
//    barrier); the counted-vmcnt/raw-s_barrier port (T3/T4) is the
//    documented next step but needs an interactive race-screen loop.
// Block = 4 output rows x 128 px x 64 o; 8 waves = (rw4, np2); grid 1024.
// x staged per 16-ch QUARTER: [row6][cblk2][slot130][ch8] = 24,960 B,
//   single-buffered; 24 tasks = 3/wave, each 8 coalesced dword loads + pkrtz.
// w per quarter via global_load_lds DMA, double-buffered (2 x 18,432 B);
//   next quarter's DMA issues before the current K-loop -> hidden under MFMA.
// LDS total 61,824 B -> 2 blocks/CU.
// Halo-padded pixel axis (slots 0/129 zeroed once) -> no bounds logic.
// All LDS ops lane-contiguous 16 B -> conflict-free.
// XCD swizzle: 1024 % 8 == 0; wg = (bid&7)*128 + bid>>3.
__global__ __launch_bounds__(512, 4) void conv_mfma(
    const float* __restrict__ x, const u16* __restrict__ wbuf,
    const float* __restrict__ bias, float* __restrict__ out) {
  __shared__ u16 xlds[12 * 130 * 8];   // 24,960 B
  __shared__ u16 wlds[2][18 * 512];    // 2 x 18,432 B

  int tid = threadIdx.x;
  int lane = tid & 63;
  int wave = tid >> 6;  // 0..7
  int bid = blockIdx.x;
  int wg = ((bid & 7) << 7) | (bid >> 3);  // bijective XCD-contiguous remap
  int nb = wg >> 5;        // batch [0,32)
  int hg = wg & 31;        // row-group [0,32)
  int h0 = hg * 4;

  int l31 = lane & 31;
  int half = lane >> 5;
  int rw = wave >> 1;   // output row within block (0..3)
  int np = wave & 1;    // ntile pair: pixels np*64 + {0,32} + l31

  // zero halo slots (0 and 129) of all 12 slabs, once; staging writes only
  // slots 1..128, so these stay zero across all 4 quarters.
  if (tid < 24) {
    int sl = tid >> 1, e = tid & 1;
    *(uint4*)&xlds[(sl * 130 + e * 129) * 8] = make_uint4(0u, 0u, 0u, 0u);
  }

  f32x16 acc[2][2] = {};  // [mt][ntile]

  // stage x channels Q*16..+15 for input rows h0-1..h0+4 -> xlds.
  // 24 tasks = (row6, cblk2, whalf2); each wave 3.
  auto stage_x = [&](int Q) {
#pragma unroll
    for (int s3 = 0; s3 < 3; ++s3) {
      int id = s3 * 8 + wave;     // 0..23
      int row = id >> 2;          // 0..5
      int cblk = (id >> 1) & 1;
      int wh = id & 1;
      int hin = h0 - 1 + row;
      int c0 = Q * 16 + cblk * 8;
      bool inb = (hin >= 0 && hin < 128);
      const float* base = x + (((size_t)(nb * 64 + c0) * 128 + hin) * 128);
      int wp = wh * 64 + lane;
      uint4 v = make_uint4(0u, 0u, 0u, 0u);
      if (inb) {
        float f[8];
#pragma unroll
        for (int j = 0; j < 8; ++j) f[j] = base[(size_t)j * 16384 + wp];
        PK p0, p1, p2, p3;
        p0.h = __builtin_amdgcn_cvt_pkrtz(f[0], f[1]);
        p1.h = __builtin_amdgcn_cvt_pkrtz(f[2], f[3]);
        p2.h = __builtin_amdgcn_cvt_pkrtz(f[4], f[5]);
        p3.h = __builtin_amdgcn_cvt_pkrtz(f[6], f[7]);
        v = make_uint4(p0.u, p1.u, p2.u, p3.u);
      }
      *(uint4*)&xlds[((row * 2 + cblk) * 130 + 1 + wp) * 8] = v;
    }
  };

  // async-DMA quarter Q's 18 A-fragments (rs9 x mt2, 1 KB each) into wl.
  auto dma_w = [&](int Q, u16* wl) {
#pragma unroll
    for (int s3 = 0; s3 < 3; ++s3) {
      int f = s3 * 8 + wave;  // 0..17 valid
      if (f < 18) {
        int gf = (f >> 1) * 8 + Q * 2 + (f & 1);  // wbuf frag (rs*4+Q)*2+mt
        gload_lds16(&wbuf[gf * 512 + lane * 8], &wl[f * 512]);
      }
    }
  };

  // 9 ktiles: per ktile {2 A + 2 B ds_read, 4 MFMA} = 1.0 reads/MFMA.
  auto kloop = [&](const u16* wl) {
#pragma unroll
    for (int r = 0; r < 3; ++r) {
      int row = rw + r;                 // staged row index 0..5
      int sb = (row * 2 + half) * 130;  // lane-half picks the quarter's cblk
#pragma unroll
      for (int s = 0; s < 3; ++s) {
        int rs = r * 3 + s;
        int ps = np * 64 + l31 + s;  // halo slot of ntile 0; ntile 1 at +32
        HU a0, a1, b0, b1;
        a0.u = *(const uint4*)&wl[(rs * 2 + 0) * 512 + lane * 8];
        a1.u = *(const uint4*)&wl[(rs * 2 + 1) * 512 + lane * 8];
        b0.u = *(const uint4*)&xlds[(sb + ps) * 8];
        b1.u = *(const uint4*)&xlds[(sb + ps + 32) * 8];
        acc[0][0] = __builtin_amdgcn_mfma_f32_32x32x16_f16(a0.h, b0.h, acc[0][0], 0, 0, 0);
        acc[0][1] = __builtin_amdgcn_mfma_f32_32x32x16_f16(a0.h, b1.h, acc[0][1], 0, 0, 0);
        acc[1][0] = __builtin_amdgcn_mfma_f32_32x32x16_f16(a1.h, b0.h, acc[1][0], 0, 0, 0);
        acc[1][1] = __builtin_amdgcn_mfma_f32_32x32x16_f16(a1.h, b1.h, acc[1][1], 0, 0, 0);
      }
    }
  };

  // ---- schedule: 4 quarters; w double-buffered (DMA hidden under kloop),
  //      x single-buffered (stage windows covered by the co-resident block) ----
  stage_x(0);
  dma_w(0, wlds[0]);
  __syncthreads();              // x(0) + w(0) ready
  dma_w(1, wlds[1]);            // in flight under kloop(0)
  kloop(wlds[0]);
  __syncthreads();              // w(1) ready, kloop(0) done -> xlds free
  stage_x(1);
  __syncthreads();              // x(1) ready
  dma_w(2, wlds[0]);            // wlds[0] free since kloop(0)
  kloop(wlds[1]);
  __syncthreads();              // w(2) ready, kloop(1) done
  stage_x(2);
  __syncthreads();              // x(2) ready
  dma_w(3, wlds[1]);
  kloop(wlds[0]);
  __syncthreads();              // w(3) ready, kloop(2) done
  stage_x(3);
  __syncthreads();              // x(3) ready
  kloop(wlds[1]);

  // ---- epilogue: C/D layout col = lane&31 (pixel), row = (reg&3)+8*(reg>>2)+4*half (o) ----
  int h = h0 + rw;
#pragma unroll
  for (int mt = 0; mt < 2; ++mt) {
#pragma unroll
    for (int i = 0; i < 2; ++i) {
      int p = np * 64 + i * 32 + l31;
      size_t ob = (size_t)nb * 64 * 16384 + (size_t)h * 128 + p;
#pragma unroll
      for (int reg = 0; reg < 16; ++reg) {
        int o = mt * 32 + (reg & 3) + 8 * (reg >> 2) + 4 * half;
        out[ob + (size_t)o * 16384] = acc[mt][i][reg] + bias[o];
      }
    }
  }
}

extern "C" void kernel_launch(void* const* d_in, const int* in_sizes, int n_in,
                              void* d_out, int out_size, void* d_ws, size_t ws_size,
                              hipStream_t stream) {
  const float* x = (const float*)d_in[0];
  const float* w = (const float*)d_in[1];
  const float* b = (const float*)d_in[2];
  float* out = (float*)d_out;
  u16* wbuf = (u16*)d_ws;  // 36864 fp16 = 73728 B of scratch

  prep_w<<<dim3(144), dim3(256), 0, stream>>>(w, wbuf);
  conv_mfma<<<dim3(1024), dim3(512), 0, stream>>>(x, wbuf, b, out);
}

// Round 15
// 251.829 us; speedup vs baseline: 1.2482x; 1.0143x over previous
//
#include <hip/hip_runtime.h>

typedef unsigned short u16;
typedef unsigned int u32;
typedef _Float16 half8 __attribute__((ext_vector_type(8)));
typedef __fp16 fp16x2 __attribute__((ext_vector_type(2)));
typedef float f32x16 __attribute__((ext_vector_type(16)));

union HU { uint4 u; half8 h; };
union PK { fp16x2 h; u32 u; };

__device__ __forceinline__ u16 f2h(float f) {
  union { _Float16 h; u16 u; } c;
  c.h = (_Float16)f;
  return c.u;
}

// async global->LDS DMA, 16 B per lane (lds dest = wave-uniform base + lane*16)
typedef const __attribute__((address_space(1))) u32 gu32;
typedef __attribute__((address_space(3))) u32 lu32;
__device__ __forceinline__ void gload_lds16(const void* g, void* l) {
  __builtin_amdgcn_global_load_lds((gu32*)g, (lu32*)l, 16, 0, 0);
}

// Pack weights (O=64, I=64, 3, 3) fp32 -> fp16 in exact A-fragment order:
// wbuf[((t*2 + mt)*64 + lane)*8 + j] = w[m][c][rs]
//   m = mt*32 + (lane&31), k = t*16 + (lane>>5)*8 + j, rs = k>>6, c = k&63
// K ordering: k = rs*64 + c (rs-major, c-minor); ktile t = rs*4 + Q (16-ch quarter).
__global__ void prep_w(const float* __restrict__ w, u16* __restrict__ wbuf) {
  int idx = blockIdx.x * 256 + threadIdx.x;  // 36864 total
  int j    = idx & 7;
  int lane = (idx >> 3) & 63;
  int mt   = (idx >> 9) & 1;
  int t    = idx >> 10;
  int m  = mt * 32 + (lane & 31);
  int k  = t * 16 + (lane >> 5) * 8 + j;
  int rs = k >> 6;
  int c  = k & 63;
  wbuf[idx] = f2h(w[(m * 64 + c) * 9 + rs]);
}

// Implicit-GEMM conv: M = O = 64, N = pixels, K = 576 in 4 quarters of 16 ch.
// v15: GEOMETRY AMORTIZATION of v6 (session best, 96.5 us).
// v6's residual cost is fixed per-block overhead (4 exposed stage windows +
// 8 barrier drains) paid per 4 output rows; no pipe is >26% busy and the
// deep-pipeline fixes are register-blocked (acc 64 + ~60 arch = 124/128
// unified budget at full occupancy — prefetch regs cannot fit, r8/r14
// analysis). This round keeps every verified inner loop byte-identical and
// doubles the output per block: 8 output rows, 1024 thr = 16 waves =
// (rw8, np2); per-output-row the windows/barriers halve and staged halo
// traffic drops 1.5x -> 1.25x (10 input rows per 8 output rows).
// LDS: x [row10][cblk2][slot130][ch8] = 41,600 B + w dbuf 2 x 18,432 B
//   = 78,464 B -> 1 block/CU x 16 waves (same 16-wave residency as v6's
//   two lockstep blocks). launch_bounds(1024,4) -> 128-reg budget/wave,
//   same per-wave footprint as v6 (VGPR ~60 + 64 acc) -> no spill.
// Wave: 64o x 64px, per ktile {2 A + 2 B ds_read_b128 -> 4 MFMA} = 1.0
// reads/MFMA, acc[2][2]. Grid 512 (32 nb x 16 hg) = exactly 2 generations.
// Halo-padded pixel axis (slots 0/129 zeroed once) -> no bounds logic.
// All LDS ops lane-contiguous 16 B -> conflict-free.
// XCD swizzle: 512 % 8 == 0; wg = (bid&7)*64 + bid>>3 (bijective).
__global__ __launch_bounds__(1024, 4) void conv_mfma(
    const float* __restrict__ x, const u16* __restrict__ wbuf,
    const float* __restrict__ bias, float* __restrict__ out) {
  __shared__ u16 xlds[10 * 2 * 130 * 8];  // 41,600 B
  __shared__ u16 wlds[2][18 * 512];       // 2 x 18,432 B

  int tid = threadIdx.x;
  int lane = tid & 63;
  int wave = tid >> 6;  // 0..15
  int bid = blockIdx.x;
  int wg = ((bid & 7) << 6) | (bid >> 3);  // bijective XCD-contiguous remap
  int nb = wg >> 4;        // batch [0,32)
  int hg = wg & 15;        // row-group [0,16)
  int h0 = hg * 8;

  int l31 = lane & 31;
  int half = lane >> 5;
  int rw = wave >> 1;   // output row within block (0..7)
  int np = wave & 1;    // ntile pair: pixels np*64 + {0,32} + l31

  // zero halo slots (0 and 129) of all 20 slabs, once; staging writes only
  // slots 1..128, so these stay zero across all 4 quarters.
  if (tid < 40) {
    int sl = tid >> 1, e = tid & 1;
    *(uint4*)&xlds[(sl * 130 + e * 129) * 8] = make_uint4(0u, 0u, 0u, 0u);
  }

  f32x16 acc[2][2] = {};  // [mt][ntile]

  // stage x channels Q*16..+15 for input rows h0-1..h0+8 -> xlds.
  // 40 tasks = (row10, cblk2, whalf2); waves 0..7 do 3, waves 8..15 do 2.
  auto stage_x = [&](int Q) {
#pragma unroll
    for (int s3 = 0; s3 < 3; ++s3) {
      int id = s3 * 16 + wave;    // 0..47, valid < 40
      if (id < 40) {
        int row = id >> 2;        // 0..9
        int cblk = (id >> 1) & 1;
        int wh = id & 1;
        int hin = h0 - 1 + row;
        int c0 = Q * 16 + cblk * 8;
        bool inb = (hin >= 0 && hin < 128);
        const float* base = x + (((size_t)(nb * 64 + c0) * 128 + hin) * 128);
        int wp = wh * 64 + lane;
        uint4 v = make_uint4(0u, 0u, 0u, 0u);
        if (inb) {
          float f[8];
#pragma unroll
          for (int j = 0; j < 8; ++j) f[j] = base[(size_t)j * 16384 + wp];
          PK p0, p1, p2, p3;
          p0.h = __builtin_amdgcn_cvt_pkrtz(f[0], f[1]);
          p1.h = __builtin_amdgcn_cvt_pkrtz(f[2], f[3]);
          p2.h = __builtin_amdgcn_cvt_pkrtz(f[4], f[5]);
          p3.h = __builtin_amdgcn_cvt_pkrtz(f[6], f[7]);
          v = make_uint4(p0.u, p1.u, p2.u, p3.u);
        }
        *(uint4*)&xlds[((row * 2 + cblk) * 130 + 1 + wp) * 8] = v;
      }
    }
  };

  // async-DMA quarter Q's 18 A-fragments (rs9 x mt2, 1 KB each) into wl.
  auto dma_w = [&](int Q, u16* wl) {
#pragma unroll
    for (int s = 0; s < 2; ++s) {
      int f = s * 16 + wave;  // 0..31, valid < 18
      if (f < 18) {
        int gf = (f >> 1) * 8 + Q * 2 + (f & 1);  // wbuf frag (rs*4+Q)*2+mt
        gload_lds16(&wbuf[gf * 512 + lane * 8], &wl[f * 512]);
      }
    }
  };

  // 9 ktiles: per ktile {2 A + 2 B ds_read, 4 MFMA} = 1.0 reads/MFMA.
  auto kloop = [&](const u16* wl) {
#pragma unroll
    for (int r = 0; r < 3; ++r) {
      int row = rw + r;                 // staged row index 0..9
      int sb = (row * 2 + half) * 130;  // lane-half picks the quarter's cblk
#pragma unroll
      for (int s = 0; s < 3; ++s) {
        int rs = r * 3 + s;
        int ps = np * 64 + l31 + s;  // halo slot of ntile 0; ntile 1 at +32
        HU a0, a1, b0, b1;
        a0.u = *(const uint4*)&wl[(rs * 2 + 0) * 512 + lane * 8];
        a1.u = *(const uint4*)&wl[(rs * 2 + 1) * 512 + lane * 8];
        b0.u = *(const uint4*)&xlds[(sb + ps) * 8];
        b1.u = *(const uint4*)&xlds[(sb + ps + 32) * 8];
        acc[0][0] = __builtin_amdgcn_mfma_f32_32x32x16_f16(a0.h, b0.h, acc[0][0], 0, 0, 0);
        acc[0][1] = __builtin_amdgcn_mfma_f32_32x32x16_f16(a0.h, b1.h, acc[0][1], 0, 0, 0);
        acc[1][0] = __builtin_amdgcn_mfma_f32_32x32x16_f16(a1.h, b0.h, acc[1][0], 0, 0, 0);
        acc[1][1] = __builtin_amdgcn_mfma_f32_32x32x16_f16(a1.h, b1.h, acc[1][1], 0, 0, 0);
      }
    }
  };

  // ---- schedule: identical dependency pattern to v6 (verified) ----
  stage_x(0);
  dma_w(0, wlds[0]);
  __syncthreads();              // x(0) + w(0) ready
  dma_w(1, wlds[1]);            // in flight under kloop(0)
  kloop(wlds[0]);
  __syncthreads();              // w(1) ready, kloop(0) done -> xlds free
  stage_x(1);
  __syncthreads();              // x(1) ready
  dma_w(2, wlds[0]);            // wlds[0] free since kloop(0)
  kloop(wlds[1]);
  __syncthreads();              // w(2) ready, kloop(1) done
  stage_x(2);
  __syncthreads();              // x(2) ready
  dma_w(3, wlds[1]);
  kloop(wlds[0]);
  __syncthreads();              // w(3) ready, kloop(2) done
  stage_x(3);
  __syncthreads();              // x(3) ready
  kloop(wlds[1]);

  // ---- epilogue: C/D layout col = lane&31 (pixel), row = (reg&3)+8*(reg>>2)+4*half (o) ----
  int h = h0 + rw;
#pragma unroll
  for (int mt = 0; mt < 2; ++mt) {
#pragma unroll
    for (int i = 0; i < 2; ++i) {
      int p = np * 64 + i * 32 + l31;
      size_t ob = (size_t)nb * 64 * 16384 + (size_t)h * 128 + p;
#pragma unroll
      for (int reg = 0; reg < 16; ++reg) {
        int o = mt * 32 + (reg & 3) + 8 * (reg >> 2) + 4 * half;
        out[ob + (size_t)o * 16384] = acc[mt][i][reg] + bias[o];
      }
    }
  }
}

extern "C" void kernel_launch(void* const* d_in, const int* in_sizes, int n_in,
                              void* d_out, int out_size, void* d_ws, size_t ws_size,
                              hipStream_t stream) {
  const float* x = (const float*)d_in[0];
  const float* w = (const float*)d_in[1];
  const float* b = (const float*)d_in[2];
  float* out = (float*)d_out;
  u16* wbuf = (u16*)d_ws;  // 36864 fp16 = 73728 B of scratch

  prep_w<<<dim3(144), dim3(256), 0, stream>>>(w, wbuf);
  conv_mfma<<<dim3(512), dim3(1024), 0, stream>>>(x, wbuf, b, out);
}